// Round 14
// baseline (213.187 us; speedup 1.0000x reference)
//
#include <hip/hip_runtime.h>
#include <hip/hip_bf16.h>
#include <cstdint>
#include <cstddef>

#define BATCH 32
#define CIN   256
#define COUT  256
#define HH    56
#define WW    56
#define HP    60      // padded rows: 0..57 read; 58/59 slack (zeroed)
#define WPAD  64      // padded cols: 0,57 are conv zero-pad; 58..63 slack (zeroed)
#define KTOT  2304    // 9 * 256
#define MTOT  100352  // 32 * 56 * 56 real output rows
#define HW    3136    // 56*56
#define NBLK  392     // MTOT / 256 (= 8 * 49)

typedef __attribute__((ext_vector_type(4))) float  f32x4;
typedef __attribute__((ext_vector_type(8))) short  short8;
typedef __attribute__((ext_vector_type(4))) short  short4v;

// ---------------- fused prep: weight repack + xq pad zeroing ----------------
// bid < 2304: WrP[kt][tg][kk][l][i] (DMA-ready BK=64 image):
//   E = kt*16384 + tg*1024 + kk*512 + l*8 + i -> n = tg*16+(l&15),
//   c = (kt&3)*64 + kk*32 + (l>>4)*8 + i, j = kt>>2.
// bid >= 2304: zero padding cells of xq (12.4 MB).
__global__ void prep_kernel(const float* __restrict__ Wsrc, unsigned short* __restrict__ WrP,
                            unsigned short* __restrict__ xq)
{
    const int bid = blockIdx.x;
    const int tid = threadIdx.x;
    if (bid < 2304) {
        int E  = bid * 256 + tid;
        int kt = E >> 14;
        int r  = E & 16383;
        int tg = r >> 10;
        int kk = (r >> 9) & 1;
        int l  = (r >> 3) & 63;
        int i  = E & 7;
        int n  = tg * 16 + (l & 15);
        int c  = (kt & 3) * 64 + kk * 32 + (l >> 4) * 8 + i;
        int j  = kt >> 2;
        float val = Wsrc[((size_t)n * CIN + c) * 9 + j];
        __hip_bfloat16 bv = __float2bfloat16(val);
        WrP[E] = *reinterpret_cast<unsigned short*>(&bv);
    } else {
        const int zbid = bid - 2304;           // 0..2815
        const int b    = zbid / 88;
        const int idx  = (zbid % 88) * 256 + tid;   // 0..22527
        const int pos  = idx >> 5;
        const int ch   = (idx & 31) * 8;
        int hp, wp;
        if (pos < 256) {                       // rows {0,57,58,59} full
            int r = pos >> 6;
            hp = (r == 0) ? 0 : 56 + r;
            wp = pos & 63;
        } else {                               // rows 1..56, cols {0,57..63}
            int i2 = pos - 256;
            int c  = i2 & 7;
            hp = (i2 >> 3) + 1;
            wp = (c == 0) ? 0 : 56 + c;
        }
        short8 z = {0, 0, 0, 0, 0, 0, 0, 0};
        *reinterpret_cast<short8*>(xq + (((size_t)b * HP + hp) * WPAD + wp) * CIN + ch) = z;
    }
}

// ---------------- BFP quantize + NCHW->padded-NHWC bf16 repack ----------------
__global__ void quant_kernel(const float* __restrict__ x, unsigned short* __restrict__ xq)
{
    const int hb  = blockIdx.x;       // 0..13
    const int b   = blockIdx.y;       // 0..31
    const int tid = threadIdx.x;
    const int hh  = tid >> 6;         // 0..3
    const int w   = tid & 63;
    const int h   = hb * 4 + hh;      // 0..55
    if (w >= WW) return;
    for (int cb = 0; cb < 8; ++cb) {
        float v[32];
        float mx = 0.f;
        const float* xp = x + (((size_t)b * CIN + cb * 32) * HH + h) * WW + w;
#pragma unroll
        for (int c = 0; c < 32; ++c) {
            float t = xp[(size_t)c * HH * WW];
            v[c] = t;
            mx = fmaxf(mx, fabsf(t));
        }
        float m = fmaxf(mx, 1e-12f);
        int e;
        frexpf(m, &e);
        e -= 1;                                  // exact floor(log2(m))
        e = (e < -64) ? -64 : ((e > 63) ? 63 : e);
        float step = exp2f((float)(e - 7));
        float inv  = exp2f((float)(7 - e));
        unsigned short qb[32];
#pragma unroll
        for (int c = 0; c < 32; ++c) {
            float q = rintf(v[c] * inv);          // round-half-even, matches jnp.round
            q = fminf(fmaxf(q, -128.f), 127.f);
            float val = q * step;                 // exactly representable in bf16
            __hip_bfloat16 bv = __float2bfloat16(val);
            qb[c] = *reinterpret_cast<unsigned short*>(&bv);
        }
        unsigned short* dst = xq + (((size_t)b * HP + (h + 1)) * WPAD + (w + 1)) * CIN + cb * 32;
#pragma unroll
        for (int i = 0; i < 4; ++i)
            *reinterpret_cast<short8*>(dst + i * 8) = *reinterpret_cast<const short8*>(qb + i * 8);
    }
}

// ======================= implicit-GEMM conv — r12 core (best measured: 142.8 us) =======================
// 256x256 tile over REAL M rows, 392 blocks, BK=64, 8 waves (2Mx4N), per-wave 128x64,
// 4 phases/K-tile, A 3-deep + B 2-deep = 160 KB, uniform counted VMWAIT(4), setprio.
// Y16: epilogue stores bf16 y (non-temporal) for the BN pass; BN stats fused via atomics.
__device__ __forceinline__ void gload_lds16(const void* g, void* l)
{
    __builtin_amdgcn_global_load_lds((const __attribute__((address_space(1))) void*)g,
                                     (__attribute__((address_space(3))) void*)l, 16, 0, 0);
}
#define VMWAIT(n) do { asm volatile("s_waitcnt vmcnt(" #n ")" ::: "memory"); } while (0)
#define PRIO(n)   __builtin_amdgcn_s_setprio(n)
#define SBAR()    __builtin_amdgcn_s_barrier()

#define MFMA_PH(p)                                                                        \
    _Pragma("unroll")                                                                     \
    for (int kk = 0; kk < 2; ++kk)                                                        \
        _Pragma("unroll")                                                                 \
        for (int jj = 0; jj < 2; ++jj)                                                    \
            _Pragma("unroll")                                                             \
            for (int ni = 0; ni < 4; ++ni)                                                \
                acc[2 * (p) + jj][ni] = __builtin_amdgcn_mfma_f32_16x16x32_bf16(          \
                    afv[jj][kk], bfv[ni][kk], acc[2 * (p) + jj][ni], 0, 0, 0);

#define LDA_PH(p)                                                                         \
    _Pragma("unroll")                                                                     \
    for (int jj = 0; jj < 2; ++jj)                                                        \
        _Pragma("unroll")                                                                 \
        for (int kk = 0; kk < 2; ++kk)                                                    \
            afv[jj][kk] = *(const short8*)(Ac + (wm * 8 + 2 * (p) + jj) * 1024 +          \
                                           kk * 512 + lane * 8);

#define KT(ktE, A3, B2, SB, SA, A3n, B2n, VMT) do {                                       \
    const int kt_ = (ktE);                                                                \
    const unsigned short* Ac = lds + (A3) * 16384;                                        \
    const unsigned short* Bc = lds + 49152 + (B2) * 16384;                                \
    short8 bfv[4][2], afv[2][2];                                                          \
    /* ---- phase 0 ---- */                                                               \
    _Pragma("unroll")                                                                     \
    for (int ni = 0; ni < 4; ++ni)                                                        \
        _Pragma("unroll")                                                                 \
        for (int kk = 0; kk < 2; ++kk)                                                    \
            bfv[ni][kk] = *(const short8*)(Bc + (wn * 4 + ni) * 1024 + kk * 512 +         \
                                           lane * 8);                                     \
    LDA_PH(0);                                                                            \
    if (SB) stgB(kt_ + 1, 0, (B2n));                                                      \
    SBAR(); PRIO(1); MFMA_PH(0); PRIO(0); SBAR();                                         \
    /* ---- phase 1 ---- */                                                               \
    LDA_PH(1);                                                                            \
    if (SB) stgB(kt_ + 1, 1, (B2n));                                                      \
    SBAR(); PRIO(1); MFMA_PH(1); PRIO(0); SBAR();                                         \
    /* ---- phase 2 ---- */                                                               \
    LDA_PH(2);                                                                            \
    if (SA) stgA(kt_ + 2, 0, (A3n));                                                      \
    SBAR(); PRIO(1); MFMA_PH(2); PRIO(0); SBAR();                                         \
    /* ---- phase 3 ---- */                                                               \
    LDA_PH(3);                                                                            \
    if (SA) stgA(kt_ + 2, 1, (A3n));                                                      \
    SBAR(); PRIO(1); MFMA_PH(3); PRIO(0);                                                 \
    VMT;                                                                                  \
    SBAR();                                                                               \
} while (0)

template <int Y16>
__global__ __launch_bounds__(512) void conv_gemm_kernel(const unsigned short* __restrict__ xq,
                                                        const unsigned short* __restrict__ WrP,
                                                        float* __restrict__ out,
                                                        unsigned short* __restrict__ y16,
                                                        float* __restrict__ sums)
{
    extern __shared__ __align__(16) unsigned short lds[];   // A: 3x16384, B: 2x16384 elems

    const int bid  = blockIdx.x;                    // 0..391
    const int blk  = (bid & 7) * 49 + (bid >> 3);   // bijective XCD swizzle (392 = 8*49)
    const int m0   = blk * 256;
    const int tid  = threadIdx.x;
    const int wv   = tid >> 6;          // 0..7
    const int lane = tid & 63;
    const int ln   = lane & 15;
    const int kg   = lane >> 4;         // 0..3
    const int wm   = wv >> 2;           // 0..1  (M half)
    const int wn   = wv & 3;            // 0..3  (N quarter)

    int abase2[2];
#pragma unroll
    for (int hh = 0; hh < 2; ++hh) {
        int row = m0 + (hh * 8 + wv) * 16 + ln;
        int bb  = row / HW;
        int hw  = row - bb * HW;
        int h   = hw / WW;
        int w   = hw - h * WW;
        abase2[hh] = ((bb * HP + h) * WPAD + w) * CIN + kg * 8;
    }

    auto stgA = [&](int kt2, int h, int a3) {
        const int j  = kt2 >> 2;
        const int kh = j / 3, kw = j - 3 * kh;
        const int aoff = (kh * WPAD + kw) * CIN + (kt2 & 3) * 64;
        unsigned short* dst = lds + a3 * 16384 + (h * 8 + wv) * 1024;
#pragma unroll
        for (int q = 0; q < 2; ++q)
            gload_lds16(xq + abase2[h] + aoff + q * 32, (void*)(dst + q * 512));
    };
    auto stgB = [&](int kt1, int h, int b2) {
        const unsigned short* src = WrP + kt1 * 16384 + (h * 8 + wv) * 1024 + lane * 8;
        unsigned short* dst = lds + 49152 + b2 * 16384 + (h * 8 + wv) * 1024;
#pragma unroll
        for (int q = 0; q < 2; ++q)
            gload_lds16(src + q * 512, (void*)(dst + q * 512));
    };

    f32x4 acc[8][4];
#pragma unroll
    for (int i = 0; i < 8; ++i)
#pragma unroll
        for (int jn = 0; jn < 4; ++jn) acc[i][jn] = (f32x4){0.f, 0.f, 0.f, 0.f};

    // prologue: A(0), A(1), B(0) fully staged (12 loads/thread)
    stgA(0, 0, 0); stgA(0, 1, 0);
    stgA(1, 0, 1); stgA(1, 1, 1);
    stgB(0, 0, 0); stgB(0, 1, 0);
    VMWAIT(0);
    SBAR();

    for (int it = 0; it < 5; ++it) {
        const int k0 = it * 6;
        KT(k0 + 0, 0, 0, 1, 1, 2, 1, VMWAIT(4));
        KT(k0 + 1, 1, 1, 1, 1, 0, 0, VMWAIT(4));
        KT(k0 + 2, 2, 0, 1, 1, 1, 1, VMWAIT(4));
        KT(k0 + 3, 0, 1, 1, 1, 2, 0, VMWAIT(4));
        KT(k0 + 4, 1, 0, 1, 1, 0, 1, VMWAIT(4));
        KT(k0 + 5, 2, 1, 1, 1, 1, 0, VMWAIT(4));
    }
    KT(30, 0, 0, 1, 1, 2, 1, VMWAIT(4));
    KT(31, 1, 1, 1, 1, 0, 0, VMWAIT(4));
    KT(32, 2, 0, 1, 1, 1, 1, VMWAIT(4));
    KT(33, 0, 1, 1, 1, 2, 0, VMWAIT(4));
    KT(34, 1, 0, 1, 0, 0, 1, VMWAIT(0));   // stages B(35) only; drain all
    KT(35, 2, 1, 0, 0, 0, 0, (void)0);     // no staging

    // epilogue: C/D col=lane&15 (n), row=(lane>>4)*4+reg (m). All rows REAL;
    // quads 4-aligned (HW,WW %4==0). Non-temporal stores (no RFO). Fused BN stats.
#pragma unroll
    for (int jn = 0; jn < 4; ++jn) {
        const int n = wn * 64 + jn * 16 + ln;
        float s = 0.f, s2 = 0.f;
#pragma unroll
        for (int i = 0; i < 8; ++i) {
            const int row = m0 + wm * 128 + i * 16 + kg * 4;
            const int bb  = row / HW;
            const int hw  = row - bb * HW;
            f32x4 v = acc[i][jn];
            s  += v[0] + v[1] + v[2] + v[3];
            s2 += v[0] * v[0] + v[1] * v[1] + v[2] * v[2] + v[3] * v[3];
            const size_t idx = (size_t)bb * (COUT * HW) + (size_t)n * HW + hw;
            if (Y16) {
                short4v hv;
#pragma unroll
                for (int r = 0; r < 4; ++r) {
                    __hip_bfloat16 bv = __float2bfloat16(v[r]);
                    hv[r] = *reinterpret_cast<short*>(&bv);
                }
                __builtin_nontemporal_store(hv, reinterpret_cast<short4v*>(&y16[idx]));
            } else {
                __builtin_nontemporal_store(v, reinterpret_cast<f32x4*>(&out[idx]));
            }
        }
        s  += __shfl_xor(s, 16);  s  += __shfl_xor(s, 32);
        s2 += __shfl_xor(s2, 16); s2 += __shfl_xor(s2, 32);
        if (kg == 0) {
            atomicAdd(&sums[n], s);
            atomicAdd(&sums[COUT + n], s2);
        }
    }
}

// ---------------- BN normalize + affine + ReLU ----------------
__global__ void bn_apply32_kernel(float* __restrict__ y, const float* __restrict__ sums,
                                  const float* __restrict__ gamma, const float* __restrict__ beta)
{
    const int o = blockIdx.x, b = blockIdx.y;
    const float N = (float)(BATCH * HH * WW);
    const float mean = sums[o] / N;
    const float var  = sums[COUT + o] / N - mean * mean;
    const float inv  = 1.f / sqrtf(var + 1e-5f);
    const float a  = gamma[o] * inv;
    const float bb = beta[o] - mean * a;
    float* p = y + ((size_t)b * COUT + o) * HW;
    for (int i = threadIdx.x; i < 784; i += 256) {
        f32x4 v = *reinterpret_cast<const f32x4*>(p + i * 4);
#pragma unroll
        for (int r = 0; r < 4; ++r) v[r] = fmaxf(v[r] * a + bb, 0.f);
        *reinterpret_cast<f32x4*>(p + i * 4) = v;
    }
}

__global__ void bn_apply16_kernel(const unsigned short* __restrict__ y16, float* __restrict__ out,
                                  const float* __restrict__ sums,
                                  const float* __restrict__ gamma, const float* __restrict__ beta)
{
    const int o = blockIdx.x, b = blockIdx.y;
    const float N = (float)(BATCH * HH * WW);
    const float mean = sums[o] / N;
    const float var  = sums[COUT + o] / N - mean * mean;
    const float inv  = 1.f / sqrtf(var + 1e-5f);
    const float a  = gamma[o] * inv;
    const float bb = beta[o] - mean * a;
    const unsigned short* p16 = y16 + ((size_t)b * COUT + o) * HW;
    float* p = out + ((size_t)b * COUT + o) * HW;
    for (int i = threadIdx.x; i < 784; i += 256) {
        short4v hv = __builtin_nontemporal_load(
            reinterpret_cast<const short4v*>(p16 + i * 4));
        f32x4 v;
#pragma unroll
        for (int r = 0; r < 4; ++r) {
            unsigned int bits = ((unsigned int)(unsigned short)hv[r]) << 16;
            float f = *reinterpret_cast<float*>(&bits);
            v[r] = fmaxf(f * a + bb, 0.f);
        }
        __builtin_nontemporal_store(v, reinterpret_cast<f32x4*>(p + i * 4));
    }
}

extern "C" void kernel_launch(void* const* d_in, const int* in_sizes, int n_in,
                              void* d_out, int out_size, void* d_ws, size_t ws_size,
                              hipStream_t stream)
{
    const float* x     = (const float*)d_in[0];
    const float* Wsrc  = (const float*)d_in[1];
    const float* gamma = (const float*)d_in[2];
    const float* beta  = (const float*)d_in[3];
    float* out = (float*)d_out;

    char* ws = (char*)d_ws;
    const size_t XQ_BYTES  = (size_t)BATCH * HP * WPAD * CIN * 2;  // 62,914,560
    const size_t WR_BYTES  = (size_t)36 * 16384 * 2;               //  1,179,648
    const size_t SUM_BYTES = 4096;
    const size_t Y16_BYTES = (size_t)BATCH * COUT * HW * 2;        // 51,380,224
    unsigned short* xq = (unsigned short*)ws;
    unsigned short* wr = (unsigned short*)(ws + XQ_BYTES);
    float* sums = (float*)(ws + XQ_BYTES + WR_BYTES);
    unsigned short* y16 = (unsigned short*)(ws + XQ_BYTES + WR_BYTES + SUM_BYTES);
    const bool useY16 = ws_size >= XQ_BYTES + WR_BYTES + SUM_BYTES + Y16_BYTES;

    hipMemsetAsync(sums, 0, 2 * COUT * sizeof(float), stream);

    prep_kernel<<<5120, 256, 0, stream>>>(Wsrc, wr, xq);
    quant_kernel<<<dim3(14, BATCH), 256, 0, stream>>>(x, xq);

    if (useY16) {
        hipFuncSetAttribute(reinterpret_cast<const void*>(&conv_gemm_kernel<1>),
                            hipFuncAttributeMaxDynamicSharedMemorySize, 163840);
        conv_gemm_kernel<1><<<NBLK, 512, 163840, stream>>>(xq, wr, out, y16, sums);
        bn_apply16_kernel<<<dim3(COUT, BATCH), 256, 0, stream>>>(y16, out, sums, gamma, beta);
    } else {
        hipFuncSetAttribute(reinterpret_cast<const void*>(&conv_gemm_kernel<0>),
                            hipFuncAttributeMaxDynamicSharedMemorySize, 163840);
        conv_gemm_kernel<0><<<NBLK, 512, 163840, stream>>>(xq, wr, out, y16, sums);
        bn_apply32_kernel<<<dim3(COUT, BATCH), 256, 0, stream>>>(out, sums, gamma, beta);
    }
}

// Round 15
// 194.560 us; speedup vs baseline: 1.0957x; 1.0957x over previous
//
#include <hip/hip_runtime.h>
#include <hip/hip_bf16.h>
#include <cstdint>
#include <cstddef>

#define BATCH 32
#define CIN   256
#define COUT  256
#define HH    56
#define WW    56
#define HP    60      // padded rows: 0..57 read; 58/59 slack (zeroed)
#define WPAD  64      // padded cols: 0,57 are conv zero-pad; 58..63 slack (zeroed)
#define KTOT  2304    // 9 * 256
#define MTOT  100352  // 32 * 56 * 56 real output rows
#define HW    3136    // 56*56
#define NBLK  392     // MTOT / 256 (= 8 * 49)

typedef __attribute__((ext_vector_type(4))) float  f32x4;
typedef __attribute__((ext_vector_type(8))) short  short8;
typedef __attribute__((ext_vector_type(4))) short  short4v;

// ---------------- fused prep: weight repack + xq pad zeroing ----------------
__global__ void prep_kernel(const float* __restrict__ Wsrc, unsigned short* __restrict__ WrP,
                            unsigned short* __restrict__ xq)
{
    const int bid = blockIdx.x;
    const int tid = threadIdx.x;
    if (bid < 2304) {
        int E  = bid * 256 + tid;
        int kt = E >> 14;
        int r  = E & 16383;
        int tg = r >> 10;
        int kk = (r >> 9) & 1;
        int l  = (r >> 3) & 63;
        int i  = E & 7;
        int n  = tg * 16 + (l & 15);
        int c  = (kt & 3) * 64 + kk * 32 + (l >> 4) * 8 + i;
        int j  = kt >> 2;
        float val = Wsrc[((size_t)n * CIN + c) * 9 + j];
        __hip_bfloat16 bv = __float2bfloat16(val);
        WrP[E] = *reinterpret_cast<unsigned short*>(&bv);
    } else {
        const int zbid = bid - 2304;           // 0..2815
        const int b    = zbid / 88;
        const int idx  = (zbid % 88) * 256 + tid;   // 0..22527
        const int pos  = idx >> 5;
        const int ch   = (idx & 31) * 8;
        int hp, wp;
        if (pos < 256) {                       // rows {0,57,58,59} full
            int r = pos >> 6;
            hp = (r == 0) ? 0 : 56 + r;
            wp = pos & 63;
        } else {                               // rows 1..56, cols {0,57..63}
            int i2 = pos - 256;
            int c  = i2 & 7;
            hp = (i2 >> 3) + 1;
            wp = (c == 0) ? 0 : 56 + c;
        }
        short8 z = {0, 0, 0, 0, 0, 0, 0, 0};
        *reinterpret_cast<short8*>(xq + (((size_t)b * HP + hp) * WPAD + wp) * CIN + ch) = z;
    }
}

// ---------------- BFP quantize + NCHW->padded-NHWC bf16 repack ----------------
__global__ void quant_kernel(const float* __restrict__ x, unsigned short* __restrict__ xq)
{
    const int hb  = blockIdx.x;       // 0..13
    const int b   = blockIdx.y;       // 0..31
    const int tid = threadIdx.x;
    const int hh  = tid >> 6;         // 0..3
    const int w   = tid & 63;
    const int h   = hb * 4 + hh;      // 0..55
    if (w >= WW) return;
    for (int cb = 0; cb < 8; ++cb) {
        float v[32];
        float mx = 0.f;
        const float* xp = x + (((size_t)b * CIN + cb * 32) * HH + h) * WW + w;
#pragma unroll
        for (int c = 0; c < 32; ++c) {
            float t = xp[(size_t)c * HH * WW];
            v[c] = t;
            mx = fmaxf(mx, fabsf(t));
        }
        float m = fmaxf(mx, 1e-12f);
        int e;
        frexpf(m, &e);
        e -= 1;                                  // exact floor(log2(m))
        e = (e < -64) ? -64 : ((e > 63) ? 63 : e);
        float step = exp2f((float)(e - 7));
        float inv  = exp2f((float)(7 - e));
        unsigned short qb[32];
#pragma unroll
        for (int c = 0; c < 32; ++c) {
            float q = rintf(v[c] * inv);          // round-half-even, matches jnp.round
            q = fminf(fmaxf(q, -128.f), 127.f);
            float val = q * step;                 // exactly representable in bf16
            __hip_bfloat16 bv = __float2bfloat16(val);
            qb[c] = *reinterpret_cast<unsigned short*>(&bv);
        }
        unsigned short* dst = xq + (((size_t)b * HP + (h + 1)) * WPAD + (w + 1)) * CIN + cb * 32;
#pragma unroll
        for (int i = 0; i < 4; ++i)
            *reinterpret_cast<short8*>(dst + i * 8) = *reinterpret_cast<const short8*>(qb + i * 8);
    }
}

// ======================= implicit-GEMM conv — r12 core (best measured: 142.8 us) =======================
// 256x256 tile over REAL M rows, 392 blocks, BK=64, 8 waves (2Mx4N), per-wave 128x64,
// 4 phases/K-tile, A 3-deep + B 2-deep = 160 KB, uniform counted VMWAIT(4), setprio.
// Y16 epilogue uses PLAIN stores (8 B NT stores write-amplify 2x: r13/r14 lesson);
// y16 then lands in L2/L3, which bn16's reads exploit.
__device__ __forceinline__ void gload_lds16(const void* g, void* l)
{
    __builtin_amdgcn_global_load_lds((const __attribute__((address_space(1))) void*)g,
                                     (__attribute__((address_space(3))) void*)l, 16, 0, 0);
}
#define VMWAIT(n) do { asm volatile("s_waitcnt vmcnt(" #n ")" ::: "memory"); } while (0)
#define PRIO(n)   __builtin_amdgcn_s_setprio(n)
#define SBAR()    __builtin_amdgcn_s_barrier()

#define MFMA_PH(p)                                                                        \
    _Pragma("unroll")                                                                     \
    for (int kk = 0; kk < 2; ++kk)                                                        \
        _Pragma("unroll")                                                                 \
        for (int jj = 0; jj < 2; ++jj)                                                    \
            _Pragma("unroll")                                                             \
            for (int ni = 0; ni < 4; ++ni)                                                \
                acc[2 * (p) + jj][ni] = __builtin_amdgcn_mfma_f32_16x16x32_bf16(          \
                    afv[jj][kk], bfv[ni][kk], acc[2 * (p) + jj][ni], 0, 0, 0);

#define LDA_PH(p)                                                                         \
    _Pragma("unroll")                                                                     \
    for (int jj = 0; jj < 2; ++jj)                                                        \
        _Pragma("unroll")                                                                 \
        for (int kk = 0; kk < 2; ++kk)                                                    \
            afv[jj][kk] = *(const short8*)(Ac + (wm * 8 + 2 * (p) + jj) * 1024 +          \
                                           kk * 512 + lane * 8);

#define KT(ktE, A3, B2, SB, SA, A3n, B2n, VMT) do {                                       \
    const int kt_ = (ktE);                                                                \
    const unsigned short* Ac = lds + (A3) * 16384;                                        \
    const unsigned short* Bc = lds + 49152 + (B2) * 16384;                                \
    short8 bfv[4][2], afv[2][2];                                                          \
    /* ---- phase 0 ---- */                                                               \
    _Pragma("unroll")                                                                     \
    for (int ni = 0; ni < 4; ++ni)                                                        \
        _Pragma("unroll")                                                                 \
        for (int kk = 0; kk < 2; ++kk)                                                    \
            bfv[ni][kk] = *(const short8*)(Bc + (wn * 4 + ni) * 1024 + kk * 512 +         \
                                           lane * 8);                                     \
    LDA_PH(0);                                                                            \
    if (SB) stgB(kt_ + 1, 0, (B2n));                                                      \
    SBAR(); PRIO(1); MFMA_PH(0); PRIO(0); SBAR();                                         \
    /* ---- phase 1 ---- */                                                               \
    LDA_PH(1);                                                                            \
    if (SB) stgB(kt_ + 1, 1, (B2n));                                                      \
    SBAR(); PRIO(1); MFMA_PH(1); PRIO(0); SBAR();                                         \
    /* ---- phase 2 ---- */                                                               \
    LDA_PH(2);                                                                            \
    if (SA) stgA(kt_ + 2, 0, (A3n));                                                      \
    SBAR(); PRIO(1); MFMA_PH(2); PRIO(0); SBAR();                                         \
    /* ---- phase 3 ---- */                                                               \
    LDA_PH(3);                                                                            \
    if (SA) stgA(kt_ + 2, 1, (A3n));                                                      \
    SBAR(); PRIO(1); MFMA_PH(3); PRIO(0);                                                 \
    VMT;                                                                                  \
    SBAR();                                                                               \
} while (0)

template <int Y16>
__global__ __launch_bounds__(512) void conv_gemm_kernel(const unsigned short* __restrict__ xq,
                                                        const unsigned short* __restrict__ WrP,
                                                        float* __restrict__ out,
                                                        unsigned short* __restrict__ y16,
                                                        float* __restrict__ sums)
{
    extern __shared__ __align__(16) unsigned short lds[];   // A: 3x16384, B: 2x16384 elems

    const int bid  = blockIdx.x;                    // 0..391
    const int blk  = (bid & 7) * 49 + (bid >> 3);   // bijective XCD swizzle (392 = 8*49)
    const int m0   = blk * 256;
    const int tid  = threadIdx.x;
    const int wv   = tid >> 6;          // 0..7
    const int lane = tid & 63;
    const int ln   = lane & 15;
    const int kg   = lane >> 4;         // 0..3
    const int wm   = wv >> 2;           // 0..1  (M half)
    const int wn   = wv & 3;            // 0..3  (N quarter)

    int abase2[2];
#pragma unroll
    for (int hh = 0; hh < 2; ++hh) {
        int row = m0 + (hh * 8 + wv) * 16 + ln;
        int bb  = row / HW;
        int hw  = row - bb * HW;
        int h   = hw / WW;
        int w   = hw - h * WW;
        abase2[hh] = ((bb * HP + h) * WPAD + w) * CIN + kg * 8;
    }

    auto stgA = [&](int kt2, int h, int a3) {
        const int j  = kt2 >> 2;
        const int kh = j / 3, kw = j - 3 * kh;
        const int aoff = (kh * WPAD + kw) * CIN + (kt2 & 3) * 64;
        unsigned short* dst = lds + a3 * 16384 + (h * 8 + wv) * 1024;
#pragma unroll
        for (int q = 0; q < 2; ++q)
            gload_lds16(xq + abase2[h] + aoff + q * 32, (void*)(dst + q * 512));
    };
    auto stgB = [&](int kt1, int h, int b2) {
        const unsigned short* src = WrP + kt1 * 16384 + (h * 8 + wv) * 1024 + lane * 8;
        unsigned short* dst = lds + 49152 + b2 * 16384 + (h * 8 + wv) * 1024;
#pragma unroll
        for (int q = 0; q < 2; ++q)
            gload_lds16(src + q * 512, (void*)(dst + q * 512));
    };

    f32x4 acc[8][4];
#pragma unroll
    for (int i = 0; i < 8; ++i)
#pragma unroll
        for (int jn = 0; jn < 4; ++jn) acc[i][jn] = (f32x4){0.f, 0.f, 0.f, 0.f};

    // prologue: A(0), A(1), B(0) fully staged (12 loads/thread)
    stgA(0, 0, 0); stgA(0, 1, 0);
    stgA(1, 0, 1); stgA(1, 1, 1);
    stgB(0, 0, 0); stgB(0, 1, 0);
    VMWAIT(0);
    SBAR();

    for (int it = 0; it < 5; ++it) {
        const int k0 = it * 6;
        KT(k0 + 0, 0, 0, 1, 1, 2, 1, VMWAIT(4));
        KT(k0 + 1, 1, 1, 1, 1, 0, 0, VMWAIT(4));
        KT(k0 + 2, 2, 0, 1, 1, 1, 1, VMWAIT(4));
        KT(k0 + 3, 0, 1, 1, 1, 2, 0, VMWAIT(4));
        KT(k0 + 4, 1, 0, 1, 1, 0, 1, VMWAIT(4));
        KT(k0 + 5, 2, 1, 1, 1, 1, 0, VMWAIT(4));
    }
    KT(30, 0, 0, 1, 1, 2, 1, VMWAIT(4));
    KT(31, 1, 1, 1, 1, 0, 0, VMWAIT(4));
    KT(32, 2, 0, 1, 1, 1, 1, VMWAIT(4));
    KT(33, 0, 1, 1, 1, 2, 0, VMWAIT(4));
    KT(34, 1, 0, 1, 0, 0, 1, VMWAIT(0));   // stages B(35) only; drain all
    KT(35, 2, 1, 0, 0, 0, 0, (void)0);     // no staging

    // epilogue: C/D col=lane&15 (n), row=(lane>>4)*4+reg (m). All rows REAL;
    // quads 4-aligned. Y16: PLAIN 8 B stores (NT would write-amplify 2x).
#pragma unroll
    for (int jn = 0; jn < 4; ++jn) {
        const int n = wn * 64 + jn * 16 + ln;
        float s = 0.f, s2 = 0.f;
#pragma unroll
        for (int i = 0; i < 8; ++i) {
            const int row = m0 + wm * 128 + i * 16 + kg * 4;
            const int bb  = row / HW;
            const int hw  = row - bb * HW;
            f32x4 v = acc[i][jn];
            s  += v[0] + v[1] + v[2] + v[3];
            s2 += v[0] * v[0] + v[1] * v[1] + v[2] * v[2] + v[3] * v[3];
            const size_t idx = (size_t)bb * (COUT * HW) + (size_t)n * HW + hw;
            if (Y16) {
                short4v hv;
#pragma unroll
                for (int r = 0; r < 4; ++r) {
                    __hip_bfloat16 bv = __float2bfloat16(v[r]);
                    hv[r] = *reinterpret_cast<short*>(&bv);
                }
                *reinterpret_cast<short4v*>(&y16[idx]) = hv;
            } else {
                __builtin_nontemporal_store(v, reinterpret_cast<f32x4*>(&out[idx]));
            }
        }
        s  += __shfl_xor(s, 16);  s  += __shfl_xor(s, 32);
        s2 += __shfl_xor(s2, 16); s2 += __shfl_xor(s2, 32);
        if (kg == 0) {
            atomicAdd(&sums[n], s);
            atomicAdd(&sums[COUT + n], s2);
        }
    }
}

// ---------------- BN normalize + affine + ReLU ----------------
__global__ void bn_apply32_kernel(float* __restrict__ y, const float* __restrict__ sums,
                                  const float* __restrict__ gamma, const float* __restrict__ beta)
{
    const int o = blockIdx.x, b = blockIdx.y;
    const float N = (float)(BATCH * HH * WW);
    const float mean = sums[o] / N;
    const float var  = sums[COUT + o] / N - mean * mean;
    const float inv  = 1.f / sqrtf(var + 1e-5f);
    const float a  = gamma[o] * inv;
    const float bb = beta[o] - mean * a;
    float* p = y + ((size_t)b * COUT + o) * HW;
    for (int i = threadIdx.x; i < 784; i += 256) {
        f32x4 v = *reinterpret_cast<const f32x4*>(p + i * 4);
#pragma unroll
        for (int r = 0; r < 4; ++r) v[r] = fmaxf(v[r] * a + bb, 0.f);
        *reinterpret_cast<f32x4*>(p + i * 4) = v;
    }
}

__global__ void bn_apply16_kernel(const unsigned short* __restrict__ y16, float* __restrict__ out,
                                  const float* __restrict__ sums,
                                  const float* __restrict__ gamma, const float* __restrict__ beta)
{
    const int o = blockIdx.x, b = blockIdx.y;
    const float N = (float)(BATCH * HH * WW);
    const float mean = sums[o] / N;
    const float var  = sums[COUT + o] / N - mean * mean;
    const float inv  = 1.f / sqrtf(var + 1e-5f);
    const float a  = gamma[o] * inv;
    const float bb = beta[o] - mean * a;
    const unsigned short* p16 = y16 + ((size_t)b * COUT + o) * HW;
    float* p = out + ((size_t)b * COUT + o) * HW;
    for (int i = threadIdx.x; i < 784; i += 256) {
        short4v hv = *reinterpret_cast<const short4v*>(p16 + i * 4);
        f32x4 v;
#pragma unroll
        for (int r = 0; r < 4; ++r) {
            unsigned int bits = ((unsigned int)(unsigned short)hv[r]) << 16;
            float f = *reinterpret_cast<float*>(&bits);
            v[r] = fmaxf(f * a + bb, 0.f);
        }
        __builtin_nontemporal_store(v, reinterpret_cast<f32x4*>(p + i * 4));
    }
}

extern "C" void kernel_launch(void* const* d_in, const int* in_sizes, int n_in,
                              void* d_out, int out_size, void* d_ws, size_t ws_size,
                              hipStream_t stream)
{
    const float* x     = (const float*)d_in[0];
    const float* Wsrc  = (const float*)d_in[1];
    const float* gamma = (const float*)d_in[2];
    const float* beta  = (const float*)d_in[3];
    float* out = (float*)d_out;

    char* ws = (char*)d_ws;
    const size_t XQ_BYTES  = (size_t)BATCH * HP * WPAD * CIN * 2;  // 62,914,560
    const size_t WR_BYTES  = (size_t)36 * 16384 * 2;               //  1,179,648
    const size_t SUM_BYTES = 4096;
    const size_t Y16_BYTES = (size_t)BATCH * COUT * HW * 2;        // 51,380,224
    unsigned short* xq = (unsigned short*)ws;
    unsigned short* wr = (unsigned short*)(ws + XQ_BYTES);
    float* sums = (float*)(ws + XQ_BYTES + WR_BYTES);
    unsigned short* y16 = (unsigned short*)(ws + XQ_BYTES + WR_BYTES + SUM_BYTES);
    const bool useY16 = ws_size >= XQ_BYTES + WR_BYTES + SUM_BYTES + Y16_BYTES;

    hipMemsetAsync(sums, 0, 2 * COUT * sizeof(float), stream);

    prep_kernel<<<5120, 256, 0, stream>>>(Wsrc, wr, xq);
    quant_kernel<<<dim3(14, BATCH), 256, 0, stream>>>(x, xq);

    if (useY16) {
        hipFuncSetAttribute(reinterpret_cast<const void*>(&conv_gemm_kernel<1>),
                            hipFuncAttributeMaxDynamicSharedMemorySize, 163840);
        conv_gemm_kernel<1><<<NBLK, 512, 163840, stream>>>(xq, wr, out, y16, sums);
        bn_apply16_kernel<<<dim3(COUT, BATCH), 256, 0, stream>>>(y16, out, sums, gamma, beta);
    } else {
        hipFuncSetAttribute(reinterpret_cast<const void*>(&conv_gemm_kernel<0>),
                            hipFuncAttributeMaxDynamicSharedMemorySize, 163840);
        conv_gemm_kernel<0><<<NBLK, 512, 163840, stream>>>(xq, wr, out, y16, sums);
        bn_apply32_kernel<<<dim3(COUT, BATCH), 256, 0, stream>>>(out, sums, gamma, beta);
    }
}